// Round 4
// baseline (128.061 us; speedup 1.0000x reference)
//
#include <hip/hip_runtime.h>

// z[l, c] = prior[0] * dic[1, 0, c]  for all l in [0, L)
//
// attention = softmax over a size-1 axis == 1.0 exactly -> output is a
// broadcast of one scaled 1024-float row. Pure write-stream kernel.
//
// R3 change vs R1/R2: back to 2048 blocks, but GRID-STRIDE row order
// (like R0, but with temporal stores -- R0 conflated nt-stores with the
// interleaved pattern). At any instant the 2048 resident blocks write one
// dense 8 MiB moving window -> sequential addresses per HBM channel ->
// row-buffer locality. This matches fillBufferAligned's access shape
// (6.5-6.9 TB/s on this chip).

typedef float f4 __attribute__((ext_vector_type(4)));

__global__ __launch_bounds__(256) void CausalPredictor_46462956208724_kernel(
    const float* __restrict__ dic,    // [2, 1, C] flat; dic_z = dic + C
    const float* __restrict__ prior,  // [1]
    float* __restrict__ out,          // [L, C] flat
    int rows)                         // L
{
    const int C4 = 256;               // float4 chunks per row; blockDim.x == 256
    const float p = prior[0];

    const f4* dz4 = reinterpret_cast<const f4*>(dic + 1024);   // dic[1:]
    f4 v = dz4[threadIdx.x];
    v *= p;

    // Grid-stride over rows: iteration k writes rows [k*grid, (k+1)*grid) --
    // a dense 8 MiB window swept front-to-back across the 512 MiB output.
    f4* p4 = reinterpret_cast<f4*>(out) + (size_t)blockIdx.x * C4 + threadIdx.x;
    const size_t stride = (size_t)gridDim.x * C4;
    const int iters = rows / gridDim.x;     // 131072 / 2048 = 64

    #pragma unroll 4
    for (int k = 0; k < iters; ++k) {
        *p4 = v;                            // 4 KiB per wave-instruction, coalesced
        p4 += stride;
    }
}

extern "C" void kernel_launch(void* const* d_in, const int* in_sizes, int n_in,
                              void* d_out, int out_size, void* d_ws, size_t ws_size,
                              hipStream_t stream) {
    // setup_inputs order: x, xm, Wy_w, Wy_b, Wz_w, Wz_b, dic, prior
    const float* dic   = (const float*)d_in[6];
    const float* prior = (const float*)d_in[7];
    float* out = (float*)d_out;

    const int C = 1024;
    const int rows = out_size / C;    // L = 131072

    const int grid = 2048;            // 8 blocks/CU, full co-residency
    CausalPredictor_46462956208724_kernel<<<grid, 256, 0, stream>>>(dic, prior, out, rows);
}

// Round 5
// 93.642 us; speedup vs baseline: 1.3676x; 1.3676x over previous
//
#include <hip/hip_runtime.h>

// z[l, c] = prior[0] * dic[1, 0, c]  for all l in [0, L)
//
// attention = softmax over a size-1 axis == 1.0 exactly -> output is a
// broadcast of one scaled 1024-float row. Pure write-stream kernel
// (512 MiB stores, ~4 KiB reads).
//
// Pattern history: grid-stride (R0/R3) = 128-132 us; per-block contiguous
// 256 KiB x 2048 blocks (R1) = 94.7 us; 1 MiB x 512 blocks (R2) = 99.1 us.
// R4: keep R1's winning shape, deepen the store pipeline: unroll 16 with
// pointer increments (global_store imm offset is 13-bit signed, so 4 KiB row
// stride can't fold into immediates -- give each store its own incremented
// pointer and 16 independent stores between loop branches).

typedef float f4 __attribute__((ext_vector_type(4)));

__global__ __launch_bounds__(256) void CausalPredictor_46462956208724_kernel(
    const float* __restrict__ dic,    // [2, 1, C] flat; dic_z = dic + C
    const float* __restrict__ prior,  // [1]
    float* __restrict__ out,          // [L, C] flat
    int rows_per_block)               // rows / gridDim.x = 64
{
    const int C4 = 256;               // float4 chunks per row; blockDim.x == 256
    const float p = prior[0];

    const f4* dz4 = reinterpret_cast<const f4*>(dic + 1024);   // dic[1:]
    f4 v = dz4[threadIdx.x];
    v *= p;

    // Block b owns rows [b*rpb, (b+1)*rpb) -- one contiguous 256 KiB region.
    f4* q = reinterpret_cast<f4*>(out)
          + (size_t)blockIdx.x * rows_per_block * C4 + threadIdx.x;

    #pragma unroll 16
    for (int r = 0; r < rows_per_block; ++r) {
        *q = v;                        // 256 threads * 16 B = 4 KiB/row, coalesced
        q += C4;
    }
}

extern "C" void kernel_launch(void* const* d_in, const int* in_sizes, int n_in,
                              void* d_out, int out_size, void* d_ws, size_t ws_size,
                              hipStream_t stream) {
    // setup_inputs order: x, xm, Wy_w, Wy_b, Wz_w, Wz_b, dic, prior
    const float* dic   = (const float*)d_in[6];
    const float* prior = (const float*)d_in[7];
    float* out = (float*)d_out;

    const int C = 1024;
    const int rows = out_size / C;    // L = 131072

    const int grid = 2048;            // 8 blocks/CU, full co-residency
    const int rows_per_block = rows / grid;   // 64
    CausalPredictor_46462956208724_kernel<<<grid, 256, 0, stream>>>(dic, prior, out, rows_per_block);
}